// Round 1
// 186.918 us; speedup vs baseline: 1.0484x; 1.0484x over previous
//
#include <hip/hip_runtime.h>
#include <hip/hip_bf16.h>

// streams: x250 (len 15000, step 4), x500 (len 30000, step 2), x1000 (len 60000, step 1)
// L = 60000, D_MODEL = 256, KERNEL = 5 taps, pad = 2. Inputs fp32, output fp32.
// Output (flat fp32): X [3,256,60000] = 46,080,000 elems; S [2,60000] = 120,000.
// Conv collapses per stream (zero-insertion upsample):
//   i=0: y = b + w2*x[p]                       (p<15000)
//   i=1: y = b + w0*x[p-1] + w2*x[p] + w4*x[p+1]   (p<30000)
//   i=2: full 5-tap                            (p<60000)
// Channel-amortized blocks: each block caches its x window in registers once,
// then loops 32 channels -> 128KB written per block setup. S fused (cg==8).
//
// R1 change: nontemporal stores -> plain (allocating) float4 stores.
// Rationale: output (184.8 MB) fits in the 256 MB Infinity Cache; nt policy
// forced direct-to-HBM streaming measured at ~2.4 TB/s vs the 6.27 TB/s the
// harness fill achieves on the same buffer. Cached stores retire at L2/L3
// speed and write back after kernel end.

#define L_OUT   60000
#define LEN0    15000
#define LEN1    30000
#define LEN2    60000
#define DMODEL  256
#define X_ELEMS (3 * DMODEL * L_OUT)

typedef float float4v __attribute__((ext_vector_type(4)));

__device__ __forceinline__ void st4(float* p, float a, float b, float c, float d) {
    float4v v; v.x = a; v.y = b; v.z = c; v.w = d;
    *(float4v*)p = v;   // plain store: allocate in L2/L3 (output fits in 256MB L3)
}

__device__ __forceinline__ float ld_or_zero(const float* __restrict__ x,
                                            int idx, int len) {
    return (idx >= 0 && idx < len) ? x[idx] : 0.0f;
}

// grid: (59 chunks of 1024 pos, 9, 3 streams) x 256 threads.
// blockIdx.y in [0,8): 32-channel group; ==8: S-output duty.
__global__ __launch_bounds__(256) void embed_kernel(
    const float* __restrict__ x250,
    const float* __restrict__ x500,
    const float* __restrict__ x1000,
    const float* __restrict__ W,   // [256,1,5]
    const float* __restrict__ b,   // [256]
    float* __restrict__ out)
{
    const int chunk = blockIdx.x;   // 0..58
    const int cg    = blockIdx.y;   // 0..8
    const int i     = blockIdx.z;   // 0..2
    const int tid   = threadIdx.x;

    if (cg == 8) {
        // ---- S duty: 177 blocks cover 120000 elems, 4/thread ----
        const int sid = i * 59 + chunk;
        const int t0  = sid * 1024 + tid * 4;
        if (t0 >= 2 * L_OUT) return;
        float ov[4];
#pragma unroll
        for (int j = 0; j < 4; ++j) {
            const int t = t0 + j;
            float val;
            if (t < L_OUT) {
                val = (t < 15000) ? 0.0f : ((t < 45000) ? 1.0f : 2.0f);  // rows
            } else {
                const int u = t - L_OUT;                                 // cols
                int iv;
                if (u < 15000)      iv = 4 * u;
                else if (u < 45000) iv = 2 * (u - 15000);
                else                iv = u - 45000;
                val = (float)iv;
            }
            ov[j] = val;
        }
        st4(out + X_ELEMS + t0, ov[0], ov[1], ov[2], ov[3]);
        return;
    }

    const int p0 = chunk * 1024 + tid * 4;
    if (p0 >= L_OUT) return;        // only chunk 58 tail threads

    const int cbase = cg * 32;
    float* dst = out + (size_t)(i * DMODEL + cbase) * L_OUT + p0;
    const int len = (i == 0) ? LEN0 : (i == 1) ? LEN1 : LEN2;

    if (p0 >= len) {
        // ---- pure-zero duty (42% of X bytes): no loads, 32 stores ----
#pragma unroll 4
        for (int ci = 0; ci < 32; ++ci) { st4(dst, 0.f, 0.f, 0.f, 0.f); dst += L_OUT; }
        return;
    }
    // NOTE: len is a multiple of 4 and p0 is a multiple of 4, so p0 < len
    // implies p0+3 < len — no per-position masking needed below.

    if (i == 0) {
        float xv[4];
#pragma unroll
        for (int j = 0; j < 4; ++j) xv[j] = x250[p0 + j];
#pragma unroll 4
        for (int ci = 0; ci < 32; ++ci) {
            const int c = cbase + ci;
            const float w2 = W[c * 5 + 2], bias = b[c];
            float y[4];
#pragma unroll
            for (int j = 0; j < 4; ++j) y[j] = fmaf(w2, xv[j], bias);
            st4(dst, y[0], y[1], y[2], y[3]);
            dst += L_OUT;
        }
    } else if (i == 1) {
        float a[6];                              // x500[p0-1 .. p0+4]
#pragma unroll
        for (int j = 0; j < 6; ++j) a[j] = ld_or_zero(x500, p0 - 1 + j, LEN1);
#pragma unroll 4
        for (int ci = 0; ci < 32; ++ci) {
            const int c = cbase + ci;
            const float w0 = W[c * 5 + 0], w2 = W[c * 5 + 2],
                        w4 = W[c * 5 + 4], bias = b[c];
            float y[4];
#pragma unroll
            for (int j = 0; j < 4; ++j) {
                float acc = fmaf(w0, a[j], bias);     // x[p-1]
                acc = fmaf(w2, a[j + 1], acc);        // x[p]
                acc = fmaf(w4, a[j + 2], acc);        // x[p+1]
                y[j] = acc;
            }
            st4(dst, y[0], y[1], y[2], y[3]);
            dst += L_OUT;
        }
    } else {
        float a[8];                              // x1000[p0-2 .. p0+5]
#pragma unroll
        for (int j = 0; j < 8; ++j) a[j] = ld_or_zero(x1000, p0 - 2 + j, LEN2);
#pragma unroll 4
        for (int ci = 0; ci < 32; ++ci) {
            const int c = cbase + ci;
            const float w0 = W[c * 5 + 0], w1 = W[c * 5 + 1], w2 = W[c * 5 + 2],
                        w3 = W[c * 5 + 3], w4 = W[c * 5 + 4], bias = b[c];
            float y[4];
#pragma unroll
            for (int j = 0; j < 4; ++j) {
                float acc = fmaf(w0, a[j], bias);
                acc = fmaf(w1, a[j + 1], acc);
                acc = fmaf(w2, a[j + 2], acc);
                acc = fmaf(w3, a[j + 3], acc);
                acc = fmaf(w4, a[j + 4], acc);
                y[j] = acc;
            }
            st4(dst, y[0], y[1], y[2], y[3]);
            dst += L_OUT;
        }
    }
}

extern "C" void kernel_launch(void* const* d_in, const int* in_sizes, int n_in,
                              void* d_out, int out_size, void* d_ws, size_t ws_size,
                              hipStream_t stream) {
    const float* x250  = (const float*)d_in[0];
    const float* x500  = (const float*)d_in[1];
    const float* x1000 = (const float*)d_in[2];
    const float* W     = (const float*)d_in[3];
    const float* b     = (const float*)d_in[4];
    float* out = (float*)d_out;

    // 59 position chunks x (8 channel groups + 1 S duty) x 3 streams
    dim3 grid(59, 9, 3);
    embed_kernel<<<grid, 256, 0, stream>>>(x250, x500, x1000, W, b, out);
}